// Round 4
// baseline (184.562 us; speedup 1.0000x reference)
//
#include <hip/hip_runtime.h>

typedef unsigned short u16;
typedef __bf16 bf16;
typedef bf16 bf16x8 __attribute__((ext_vector_type(8)));
typedef float f32x4 __attribute__((ext_vector_type(4)));

#define SEQ     2048
#define BATCH   2
#define DM      1024
#define DI      1024
#define NROW    (BATCH*SEQ)      // 4096
#define NSTATE  16
#define NCHUNK  64
#define CLEN    32               // SEQ / NCHUNK

static_assert(SEQ == NCHUNK * CLEN, "chunking must cover SEQ");

__device__ __forceinline__ u16 f2bf(float f) {
  unsigned u = __builtin_bit_cast(unsigned, f);
  u += 0x7FFFu + ((u >> 16) & 1u);   // round-to-nearest-even
  return (u16)(u >> 16);
}
__device__ __forceinline__ float sigm(float x) { return 1.f / (1.f + __expf(-x)); }

// ---------------- fused fp32 -> bf16 convert for all 4 tensors ----------------
// segments (in float4 units): x 1048576 | W_in 524288 | W_dt 262144 | W_out 262144
__global__ __launch_bounds__(256) void k_cvt_all(
    const float* __restrict__ x, const float* __restrict__ Win,
    const float* __restrict__ Wdt, const float* __restrict__ Wout,
    u16* __restrict__ xbf, u16* __restrict__ winbf,
    u16* __restrict__ wdtbf, u16* __restrict__ woutbf)
{
  long i = (long)blockIdx.x * 256 + threadIdx.x;
  const float* src; u16* dst; long off;
  if (i < 1048576)            { src = x;    dst = xbf;    off = i; }
  else if (i < 1572864)       { src = Win;  dst = winbf;  off = i - 1048576; }
  else if (i < 1835008)       { src = Wdt;  dst = wdtbf;  off = i - 1572864; }
  else                        { src = Wout; dst = woutbf; off = i - 1835008; }
  float4 v = reinterpret_cast<const float4*>(src)[off];
  ushort4 o;
  o.x = f2bf(v.x); o.y = f2bf(v.y); o.z = f2bf(v.z); o.w = f2bf(v.w);
  reinterpret_cast<ushort4*>(dst)[off] = o;
}

// ---------------- bf16 MFMA GEMM: C[M][N] = A[M][K] * B[N][K]^T ----------------
// Depth-3 prefetch pipeline (T4 counted-vmcnt): 4 LDS buffers, never drain
// vmcnt to 0 in the main loop. Fused "s_waitcnt vmcnt(2L); s_barrier" in one
// asm volatile w/ memory clobber so LDS reads can't hoist above it.
#define BM 128
#define BK 32
#define NBUF 4

__device__ __forceinline__ void gload16(const u16* g, u16* l) {
  __builtin_amdgcn_global_load_lds((const __attribute__((address_space(1))) void*)g,
                                   (__attribute__((address_space(3))) void*)l,
                                   16, 0, 0);
}

template<int EPI, int BN>
__global__ __launch_bounds__(256) void k_gemm(
    const u16* __restrict__ A, const u16* __restrict__ B,
    float* __restrict__ out0, float* __restrict__ out1,
    const float* __restrict__ bias, int M, int N, int K)
{
  __shared__ __align__(16) u16 sA[NBUF * BM * BK];
  __shared__ __align__(16) u16 sB[NBUF * BN * BK];
  const int t = threadIdx.x;
  const int wave = t >> 6, lane = t & 63;
  const int lr = lane & 15, kb = lane >> 4;
  const int wr = wave >> 1, wc = wave & 1;
  const long bm = (long)blockIdx.y * BM, bn = (long)blockIdx.x * BN;

  constexpr int LPS = BM / 64 + BN / 64;    // gload_lds per thread per STAGE

  f32x4 acc[4][BN / 32] = {};

  const int srow = t >> 2;
  const int scol = (t & 3) * 8;
  const u16* gA0 = A + (bm + srow) * (long)K + scol;
  const u16* gB0 = B + (bn + srow) * (long)K + scol;

  // thread t writes LDS linear u16 offset t*8 within its 64-row block
  auto STAGE = [&](int buf, int k0) {
    #pragma unroll
    for (int i = 0; i < BM / 64; ++i)
      gload16(gA0 + (long)i * 64 * K + k0,
              &sA[buf * (BM * BK) + i * (64 * BK) + wave * 512]);
    #pragma unroll
    for (int i = 0; i < BN / 64; ++i)
      gload16(gB0 + (long)i * 64 * K + k0,
              &sB[buf * (BN * BK) + i * (64 * BK) + wave * 512]);
  };

  const int NT = K / BK;
  STAGE(0, 0);
  STAGE(1, BK);
  STAGE(2, 2 * BK);
  int cur = 0;
  for (int tt = 0; tt < NT; ++tt) {
    // wait: tile tt's loads done (tiles tt+1, tt+2 stay in flight = 2*LPS)
    asm volatile("s_waitcnt vmcnt(%0)\n\ts_barrier" :: "i"(2 * LPS) : "memory");
    // prefetch tile tt+3 into slot (cur+3)&3 == (tt+3)%4 (dummy k0=0 at tail)
    const int pre = (cur + 3) & 3;
    const int kpre = (tt + 3 < NT) ? (tt + 3) * BK : 0;
    STAGE(pre, kpre);
    const u16* pa = &sA[cur * (BM * BK) + (wr * 64 + lr) * BK + kb * 8];
    const u16* pb = &sB[cur * (BN * BK) + (wc * (BN / 2) + lr) * BK + kb * 8];
    bf16x8 af[4], bfr[BN / 32];
    #pragma unroll
    for (int mi = 0; mi < 4; ++mi)
      af[mi] = *reinterpret_cast<const bf16x8*>(pa + mi * 16 * BK);
    #pragma unroll
    for (int ni = 0; ni < BN / 32; ++ni)
      bfr[ni] = *reinterpret_cast<const bf16x8*>(pb + ni * 16 * BK);
    #pragma unroll
    for (int mi = 0; mi < 4; ++mi)
      #pragma unroll
      for (int ni = 0; ni < BN / 32; ++ni)
        acc[mi][ni] = __builtin_amdgcn_mfma_f32_16x16x32_bf16(af[mi], bfr[ni], acc[mi][ni], 0, 0, 0);
    cur = (cur + 1) & 3;
  }

  #pragma unroll
  for (int mi = 0; mi < 4; ++mi) {
    const long row0 = bm + wr * 64 + mi * 16 + kb * 4;   // C/D: row=(lane>>4)*4+j
    #pragma unroll
    for (int ni = 0; ni < BN / 32; ++ni) {
      const long col = bn + wc * (BN / 2) + ni * 16 + lr; // C/D: col=lane&15
      #pragma unroll
      for (int j = 0; j < 4; ++j) {
        const float v = acc[mi][ni][j];
        const long r = row0 + j;
        if (EPI == 0) {
          out0[r * N + col] = v;
        } else if (EPI == 1) {
          if (col < DI) out0[r * DI + col] = v;
          else          out1[r * DI + (col - DI)] = v * sigm(v);
        } else {
          float z = v + bias[col];
          out0[r * N + col] = fmaxf(z, 0.f) + log1pf(__expf(-fabsf(z)));
        }
      }
    }
  }
}

// ---------------- causal depthwise conv (K=4) + silu ----------------
__global__ void k_conv(const float* __restrict__ xproj, const float* __restrict__ convw,
                       const float* __restrict__ convb, float* __restrict__ xc,
                       u16* __restrict__ xcbf)
{
  const int idx = blockIdx.x * 256 + threadIdx.x;   // (m,d), m = b*SEQ+l
  const int d = idx & (DI - 1);
  const int m = idx >> 10;
  const int l = m & (SEQ - 1);
  float acc = convb[d];
  #pragma unroll
  for (int k = 0; k < 4; ++k) {
    int ls = l + k - 3;
    if (ls >= 0)
      acc = fmaf(convw[d * 4 + k], xproj[(long)(m + k - 3) * DI + d], acc);
  }
  float s = acc * sigm(acc);
  xc[idx] = s;
  xcbf[idx] = f2bf(s);
}

// ---------------- selective scan, chunked ----------------
__global__ __launch_bounds__(256) void k_scanA(
    const float* __restrict__ delta, const float* __restrict__ xc,
    const float* __restrict__ A_log, const float* __restrict__ Bp,
    float* __restrict__ hfin, float* __restrict__ sumdt_buf)
{
  const int tid = threadIdx.x, blk = blockIdx.x;    // 512 blocks
  const int d = (blk & 3) * 256 + tid;
  const int c = (blk >> 2) & (NCHUNK - 1);
  const int b = blk >> 8;
  float Aa[NSTATE], Bb[NSTATE], h[NSTATE];
  #pragma unroll
  for (int n = 0; n < NSTATE; ++n) {
    Aa[n] = -__expf(A_log[d * NSTATE + n]);
    Bb[n] = Bp[d * NSTATE + n];
    h[n] = 0.f;
  }
  const long base = ((long)(b * SEQ + c * CLEN)) * DI + d;
  float sdt = 0.f;
  for (int i = 0; i < CLEN; ++i) {
    float dt = delta[base + (long)i * DI];
    float x  = xc[base + (long)i * DI];
    sdt += dt;
    float dx = dt * x;
    #pragma unroll
    for (int n = 0; n < NSTATE; ++n) {
      float da = __expf(dt * Aa[n]);
      h[n] = fmaf(da, h[n], dx * Bb[n]);
    }
  }
  const long sb = ((long)(b * NCHUNK + c) * NSTATE) * DI + d;
  #pragma unroll
  for (int n = 0; n < NSTATE; ++n) hfin[sb + (long)n * DI] = h[n];
  sumdt_buf[(long)(b * NCHUNK + c) * DI + d] = sdt;
}

__global__ __launch_bounds__(256) void k_combine(
    const float* __restrict__ hfin, const float* __restrict__ sumdt_buf,
    const float* __restrict__ A_log, float* __restrict__ hstart)
{
  const int idx = blockIdx.x * 256 + threadIdx.x;   // 32768 threads
  const int d = idx & (DI - 1);
  const int n = (idx >> 10) & (NSTATE - 1);
  const int b = idx >> 14;
  const float Aa = -__expf(A_log[d * NSTATE + n]);
  float h = 0.f;
  for (int c = 0; c < NCHUNK; ++c) {
    const long sb = ((long)(b * NCHUNK + c) * NSTATE + n) * DI + d;
    hstart[sb] = h;
    float sdt = sumdt_buf[(long)(b * NCHUNK + c) * DI + d];
    h = fmaf(__expf(Aa * sdt), h, hfin[sb]);
  }
}

__global__ __launch_bounds__(256) void k_scanB(
    const float* __restrict__ delta, const float* __restrict__ xc,
    const float* __restrict__ A_log, const float* __restrict__ Bp,
    const float* __restrict__ Cp, const float* __restrict__ Dp,
    const float* __restrict__ sres, const float* __restrict__ hstart,
    u16* __restrict__ gated)
{
  const int tid = threadIdx.x, blk = blockIdx.x;    // 512 blocks
  const int d = (blk & 3) * 256 + tid;
  const int c = (blk >> 2) & (NCHUNK - 1);
  const int b = blk >> 8;
  float Aa[NSTATE], Bb[NSTATE], Cc[NSTATE], h[NSTATE];
  #pragma unroll
  for (int n = 0; n < NSTATE; ++n) {
    Aa[n] = -__expf(A_log[d * NSTATE + n]);
    Bb[n] = Bp[d * NSTATE + n];
    Cc[n] = Cp[d * NSTATE + n];
  }
  const float Dd = Dp[d];
  const long sb = ((long)(b * NCHUNK + c) * NSTATE) * DI + d;
  #pragma unroll
  for (int n = 0; n < NSTATE; ++n) h[n] = hstart[sb + (long)n * DI];
  const long base = ((long)(b * SEQ + c * CLEN)) * DI + d;
  for (int i = 0; i < CLEN; ++i) {
    float dt = delta[base + (long)i * DI];
    float x  = xc[base + (long)i * DI];
    float dx = dt * x;
    float y = 0.f;
    #pragma unroll
    for (int n = 0; n < NSTATE; ++n) {
      float da = __expf(dt * Aa[n]);
      h[n] = fmaf(da, h[n], dx * Bb[n]);
      y = fmaf(h[n], Cc[n], y);
    }
    float xs = fmaf(x, Dd, y);
    float g = xs * sres[base + (long)i * DI];
    gated[base + (long)i * DI] = f2bf(g);
  }
}

// ---------------- host launch ----------------
extern "C" void kernel_launch(void* const* d_in, const int* in_sizes, int n_in,
                              void* d_out, int out_size, void* d_ws, size_t ws_size,
                              hipStream_t stream)
{
  const float* x      = (const float*)d_in[0];
  const float* W_in   = (const float*)d_in[1];
  const float* conv_w = (const float*)d_in[2];
  const float* conv_b = (const float*)d_in[3];
  const float* W_dt   = (const float*)d_in[4];
  const float* b_dt   = (const float*)d_in[5];
  const float* A_log  = (const float*)d_in[6];
  const float* Bp     = (const float*)d_in[7];
  const float* Cp     = (const float*)d_in[8];
  const float* Dp     = (const float*)d_in[9];
  const float* W_out  = (const float*)d_in[10];
  float* out = (float*)d_out;

  const long MD = (long)NROW * DI;          // 4194304

  char* ws = (char*)d_ws;
  float* silu_res = (float*)ws;             ws += MD * 4;
  float* xc_f32   = (float*)ws;             ws += MD * 4;
  float* delta    = (float*)ws;             ws += MD * 4;   // also x_proj
  u16*   xc_bf    = (u16*)ws;               ws += MD * 2;
  u16*   xbf      = (u16*)ws;               ws += MD * 2;   // also gated_bf
  u16*   Win_bf   = (u16*)ws;               ws += (long)2 * DI * DM * 2;
  u16*   Wdt_bf   = (u16*)ws;               ws += (long)DI * DI * 2;
  u16*   Wout_bf  = (u16*)ws;               ws += (long)DM * DI * 2;
  float* hfin     = (float*)ws;             ws += (long)BATCH * NCHUNK * NSTATE * DI * 4;
  float* sumdt    = (float*)ws;             ws += (long)BATCH * NCHUNK * DI * 4;
  float* hstart   = (float*)ws;             ws += (long)BATCH * NCHUNK * NSTATE * DI * 4;

  float* x_proj = delta;    // alias: x_proj dead before delta is written
  u16*   gated  = xbf;      // alias: x_bf16 dead before gated is written

  // 1) fused fp32 -> bf16 conversion (x, W_in, W_dt, W_out): 2M float4
  k_cvt_all<<<dim3(8192), dim3(256), 0, stream>>>(
      x, W_in, W_dt, W_out, xbf, Win_bf, Wdt_bf, Wout_bf);

  // 2) GEMM1: xr = x @ W_in^T; split -> x_proj, silu_res   (grid 16x32 = 512)
  k_gemm<1, 128><<<dim3(2 * DI / 128, NROW / BM), dim3(256), 0, stream>>>(
      xbf, Win_bf, x_proj, silu_res, nullptr, NROW, 2 * DI, DM);

  // 3) causal depthwise conv + silu
  k_conv<<<dim3((unsigned)(MD / 256)), dim3(256), 0, stream>>>(x_proj, conv_w, conv_b, xc_f32, xc_bf);

  // 4) GEMM2: delta = softplus(xc @ W_dt^T + b_dt)          (grid 16x32 = 512)
  k_gemm<2, 64><<<dim3(DI / 64, NROW / BM), dim3(256), 0, stream>>>(
      xc_bf, Wdt_bf, delta, nullptr, b_dt, NROW, DI, DI);

  // 5) chunked selective scan
  k_scanA<<<dim3(BATCH * NCHUNK * (DI / 256)), dim3(256), 0, stream>>>(
      delta, xc_f32, A_log, Bp, hfin, sumdt);
  k_combine<<<dim3(BATCH * NSTATE * DI / 256), dim3(256), 0, stream>>>(
      hfin, sumdt, A_log, hstart);
  k_scanB<<<dim3(BATCH * NCHUNK * (DI / 256)), dim3(256), 0, stream>>>(
      delta, xc_f32, A_log, Bp, Cp, Dp, silu_res, hstart, gated);

  // 6) GEMM3: out = gated @ W_out^T                          (grid 16x32 = 512)
  k_gemm<0, 64><<<dim3(DM / 64, NROW / BM), dim3(256), 0, stream>>>(
      gated, Wout_bf, out, nullptr, nullptr, NROW, DM, DI);
}

// Round 5
// 168.234 us; speedup vs baseline: 1.0971x; 1.0971x over previous
//
#include <hip/hip_runtime.h>

typedef unsigned short u16;
typedef __bf16 bf16;
typedef bf16 bf16x8 __attribute__((ext_vector_type(8)));
typedef float f32x4 __attribute__((ext_vector_type(4)));

#define SEQ     2048
#define BATCH   2
#define DM      1024
#define DI      1024
#define NROW    (BATCH*SEQ)      // 4096
#define NSTATE  16
#define NCHUNK  64
#define CLEN    32               // SEQ / NCHUNK
#define BK      32

static_assert(SEQ == NCHUNK * CLEN, "chunking must cover SEQ");

__device__ __forceinline__ u16 f2bf(float f) {
  unsigned u = __builtin_bit_cast(unsigned, f);
  u += 0x7FFFu + ((u >> 16) & 1u);   // round-to-nearest-even
  return (u16)(u >> 16);
}
__device__ __forceinline__ float sigm(float x) { return 1.f / (1.f + __expf(-x)); }

// ---------------- fused fp32 -> bf16 convert for all 4 tensors ----------------
// segments (in float4 units): x 1048576 | W_in 524288 | W_dt 262144 | W_out 262144
__global__ __launch_bounds__(256) void k_cvt_all(
    const float* __restrict__ x, const float* __restrict__ Win,
    const float* __restrict__ Wdt, const float* __restrict__ Wout,
    u16* __restrict__ xbf, u16* __restrict__ winbf,
    u16* __restrict__ wdtbf, u16* __restrict__ woutbf)
{
  long i = (long)blockIdx.x * 256 + threadIdx.x;
  const float* src; u16* dst; long off;
  if (i < 1048576)            { src = x;    dst = xbf;    off = i; }
  else if (i < 1572864)       { src = Win;  dst = winbf;  off = i - 1048576; }
  else if (i < 1835008)       { src = Wdt;  dst = wdtbf;  off = i - 1572864; }
  else                        { src = Wout; dst = woutbf; off = i - 1835008; }
  float4 v = reinterpret_cast<const float4*>(src)[off];
  ushort4 o;
  o.x = f2bf(v.x); o.y = f2bf(v.y); o.z = f2bf(v.z); o.w = f2bf(v.w);
  reinterpret_cast<ushort4*>(dst)[off] = o;
}

// ---------------- bf16 MFMA GEMM: C[M][N] = A[M][K] * B[N][K]^T ----------------
// 2-buffer prefetch loop (round-3 proven structure), small tiles for
// 4 blocks/CU, 1-D grid with bijective XCD swizzle (T1).
// EPI 0: plain fp32 store   EPI 1: split x_proj / silu(res)   EPI 2: softplus+bias

__device__ __forceinline__ void gload16(const u16* g, u16* l) {
  __builtin_amdgcn_global_load_lds((const __attribute__((address_space(1))) void*)g,
                                   (__attribute__((address_space(3))) void*)l,
                                   16, 0, 0);
}

template<int EPI, int BM, int BN, int GX>
__global__ __launch_bounds__(256, 4) void k_gemm(
    const u16* __restrict__ A, const u16* __restrict__ B,
    float* __restrict__ out0, float* __restrict__ out1,
    const float* __restrict__ bias, int M, int N, int K)
{
  constexpr int MI_ = BM / 32;     // M-frags per wave (2x2 wave grid)
  constexpr int NI_ = BN / 32;     // N-frags per wave
  __shared__ __align__(16) u16 sA[2 * BM * BK];
  __shared__ __align__(16) u16 sB[2 * BN * BK];
  const int t = threadIdx.x;
  const int wave = t >> 6, lane = t & 63;
  const int lr = lane & 15, kb = lane >> 4;
  const int wr = wave >> 1, wc = wave & 1;

  // XCD-aware bijective swizzle: contiguous wg-chunks per XCD (nwg % 8 == 0)
  const int nwg = gridDim.x;
  const int bid = blockIdx.x;
  const int wg  = (bid & 7) * (nwg >> 3) + (bid >> 3);
  const long bm = (long)(wg / GX) * BM;
  const long bn = (long)(wg % GX) * BN;

  f32x4 acc[MI_][NI_] = {};

  const int srow = t >> 2;          // 0..63
  const int scol = (t & 3) * 8;     // 0,8,16,24
  const u16* gA0 = A + (bm + srow) * (long)K + scol;
  const u16* gB0 = B + (bn + srow) * (long)K + scol;

  // thread t writes LDS linear u16 offset t*8 within its 64-row block
  auto STAGE = [&](int buf, int k0) {
    #pragma unroll
    for (int i = 0; i < BM / 64; ++i)
      gload16(gA0 + (long)i * 64 * K + k0,
              &sA[buf * (BM * BK) + i * (64 * BK) + wave * 512]);
    #pragma unroll
    for (int i = 0; i < BN / 64; ++i)
      gload16(gB0 + (long)i * 64 * K + k0,
              &sB[buf * (BN * BK) + i * (64 * BK) + wave * 512]);
  };

  STAGE(0, 0);
  __syncthreads();
  int cur = 0;
  for (int k0 = 0; k0 < K; k0 += BK) {
    if (k0 + BK < K) STAGE(cur ^ 1, k0 + BK);   // prefetch next tile
    const u16* pa = &sA[cur * (BM * BK) + (wr * (BM / 2) + lr) * BK + kb * 8];
    const u16* pb = &sB[cur * (BN * BK) + (wc * (BN / 2) + lr) * BK + kb * 8];
    bf16x8 af[MI_], bfr[NI_];
    #pragma unroll
    for (int mi = 0; mi < MI_; ++mi)
      af[mi] = *reinterpret_cast<const bf16x8*>(pa + mi * 16 * BK);
    #pragma unroll
    for (int ni = 0; ni < NI_; ++ni)
      bfr[ni] = *reinterpret_cast<const bf16x8*>(pb + ni * 16 * BK);
    #pragma unroll
    for (int mi = 0; mi < MI_; ++mi)
      #pragma unroll
      for (int ni = 0; ni < NI_; ++ni)
        acc[mi][ni] = __builtin_amdgcn_mfma_f32_16x16x32_bf16(af[mi], bfr[ni], acc[mi][ni], 0, 0, 0);
    __syncthreads();   // drains vmcnt(0): next buf staged; cur reads complete
    cur ^= 1;
  }

  #pragma unroll
  for (int mi = 0; mi < MI_; ++mi) {
    const long row0 = bm + wr * (BM / 2) + mi * 16 + kb * 4;  // C/D row=(lane>>4)*4+j
    #pragma unroll
    for (int ni = 0; ni < NI_; ++ni) {
      const long col = bn + wc * (BN / 2) + ni * 16 + lr;     // C/D col=lane&15
      #pragma unroll
      for (int j = 0; j < 4; ++j) {
        const float v = acc[mi][ni][j];
        const long r = row0 + j;
        if (EPI == 0) {
          out0[r * N + col] = v;
        } else if (EPI == 1) {
          if (col < DI) out0[r * DI + col] = v;
          else          out1[r * DI + (col - DI)] = v * sigm(v);
        } else {
          float z = v + bias[col];
          out0[r * N + col] = fmaxf(z, 0.f) + log1pf(__expf(-fabsf(z)));
        }
      }
    }
  }
}

// ---------------- causal depthwise conv (K=4) + silu ----------------
__global__ void k_conv(const float* __restrict__ xproj, const float* __restrict__ convw,
                       const float* __restrict__ convb, float* __restrict__ xc,
                       u16* __restrict__ xcbf)
{
  const int idx = blockIdx.x * 256 + threadIdx.x;   // (m,d), m = b*SEQ+l
  const int d = idx & (DI - 1);
  const int m = idx >> 10;
  const int l = m & (SEQ - 1);
  float acc = convb[d];
  #pragma unroll
  for (int k = 0; k < 4; ++k) {
    int ls = l + k - 3;
    if (ls >= 0)
      acc = fmaf(convw[d * 4 + k], xproj[(long)(m + k - 3) * DI + d], acc);
  }
  float s = acc * sigm(acc);
  xc[idx] = s;
  xcbf[idx] = f2bf(s);
}

// ---------------- selective scan, chunked ----------------
__global__ __launch_bounds__(256) void k_scanA(
    const float* __restrict__ delta, const float* __restrict__ xc,
    const float* __restrict__ A_log, const float* __restrict__ Bp,
    float* __restrict__ hfin, float* __restrict__ sumdt_buf)
{
  const int tid = threadIdx.x, blk = blockIdx.x;    // 512 blocks
  const int d = (blk & 3) * 256 + tid;
  const int c = (blk >> 2) & (NCHUNK - 1);
  const int b = blk >> 8;
  float Aa[NSTATE], Bb[NSTATE], h[NSTATE];
  #pragma unroll
  for (int n = 0; n < NSTATE; ++n) {
    Aa[n] = -__expf(A_log[d * NSTATE + n]);
    Bb[n] = Bp[d * NSTATE + n];
    h[n] = 0.f;
  }
  const long base = ((long)(b * SEQ + c * CLEN)) * DI + d;
  float sdt = 0.f;
  for (int i = 0; i < CLEN; ++i) {
    float dt = delta[base + (long)i * DI];
    float x  = xc[base + (long)i * DI];
    sdt += dt;
    float dx = dt * x;
    #pragma unroll
    for (int n = 0; n < NSTATE; ++n) {
      float da = __expf(dt * Aa[n]);
      h[n] = fmaf(da, h[n], dx * Bb[n]);
    }
  }
  const long sb = ((long)(b * NCHUNK + c) * NSTATE) * DI + d;
  #pragma unroll
  for (int n = 0; n < NSTATE; ++n) hfin[sb + (long)n * DI] = h[n];
  sumdt_buf[(long)(b * NCHUNK + c) * DI + d] = sdt;
}

__global__ __launch_bounds__(256) void k_combine(
    const float* __restrict__ hfin, const float* __restrict__ sumdt_buf,
    const float* __restrict__ A_log, float* __restrict__ hstart)
{
  const int idx = blockIdx.x * 256 + threadIdx.x;   // 32768 threads
  const int d = idx & (DI - 1);
  const int n = (idx >> 10) & (NSTATE - 1);
  const int b = idx >> 14;
  const float Aa = -__expf(A_log[d * NSTATE + n]);
  float h = 0.f;
  for (int c = 0; c < NCHUNK; ++c) {
    const long sb = ((long)(b * NCHUNK + c) * NSTATE + n) * DI + d;
    hstart[sb] = h;
    float sdt = sumdt_buf[(long)(b * NCHUNK + c) * DI + d];
    h = fmaf(__expf(Aa * sdt), h, hfin[sb]);
  }
}

__global__ __launch_bounds__(256) void k_scanB(
    const float* __restrict__ delta, const float* __restrict__ xc,
    const float* __restrict__ A_log, const float* __restrict__ Bp,
    const float* __restrict__ Cp, const float* __restrict__ Dp,
    const float* __restrict__ sres, const float* __restrict__ hstart,
    u16* __restrict__ gated)
{
  const int tid = threadIdx.x, blk = blockIdx.x;    // 512 blocks
  const int d = (blk & 3) * 256 + tid;
  const int c = (blk >> 2) & (NCHUNK - 1);
  const int b = blk >> 8;
  float Aa[NSTATE], Bb[NSTATE], Cc[NSTATE], h[NSTATE];
  #pragma unroll
  for (int n = 0; n < NSTATE; ++n) {
    Aa[n] = -__expf(A_log[d * NSTATE + n]);
    Bb[n] = Bp[d * NSTATE + n];
    Cc[n] = Cp[d * NSTATE + n];
  }
  const float Dd = Dp[d];
  const long sb = ((long)(b * NCHUNK + c) * NSTATE) * DI + d;
  #pragma unroll
  for (int n = 0; n < NSTATE; ++n) h[n] = hstart[sb + (long)n * DI];
  const long base = ((long)(b * SEQ + c * CLEN)) * DI + d;
  for (int i = 0; i < CLEN; ++i) {
    float dt = delta[base + (long)i * DI];
    float x  = xc[base + (long)i * DI];
    float dx = dt * x;
    float y = 0.f;
    #pragma unroll
    for (int n = 0; n < NSTATE; ++n) {
      float da = __expf(dt * Aa[n]);
      h[n] = fmaf(da, h[n], dx * Bb[n]);
      y = fmaf(h[n], Cc[n], y);
    }
    float xs = fmaf(x, Dd, y);
    float g = xs * sres[base + (long)i * DI];
    gated[base + (long)i * DI] = f2bf(g);
  }
}

// ---------------- host launch ----------------
extern "C" void kernel_launch(void* const* d_in, const int* in_sizes, int n_in,
                              void* d_out, int out_size, void* d_ws, size_t ws_size,
                              hipStream_t stream)
{
  const float* x      = (const float*)d_in[0];
  const float* W_in   = (const float*)d_in[1];
  const float* conv_w = (const float*)d_in[2];
  const float* conv_b = (const float*)d_in[3];
  const float* W_dt   = (const float*)d_in[4];
  const float* b_dt   = (const float*)d_in[5];
  const float* A_log  = (const float*)d_in[6];
  const float* Bp     = (const float*)d_in[7];
  const float* Cp     = (const float*)d_in[8];
  const float* Dp     = (const float*)d_in[9];
  const float* W_out  = (const float*)d_in[10];
  float* out = (float*)d_out;

  const long MD = (long)NROW * DI;          // 4194304

  char* ws = (char*)d_ws;
  float* silu_res = (float*)ws;             ws += MD * 4;
  float* xc_f32   = (float*)ws;             ws += MD * 4;
  float* delta    = (float*)ws;             ws += MD * 4;   // also x_proj
  u16*   xc_bf    = (u16*)ws;               ws += MD * 2;
  u16*   xbf      = (u16*)ws;               ws += MD * 2;   // also gated_bf
  u16*   Win_bf   = (u16*)ws;               ws += (long)2 * DI * DM * 2;
  u16*   Wdt_bf   = (u16*)ws;               ws += (long)DI * DI * 2;
  u16*   Wout_bf  = (u16*)ws;               ws += (long)DM * DI * 2;
  float* hfin     = (float*)ws;             ws += (long)BATCH * NCHUNK * NSTATE * DI * 4;
  float* sumdt    = (float*)ws;             ws += (long)BATCH * NCHUNK * DI * 4;
  float* hstart   = (float*)ws;             ws += (long)BATCH * NCHUNK * NSTATE * DI * 4;

  float* x_proj = delta;    // alias: x_proj dead before delta is written
  u16*   gated  = xbf;      // alias: x_bf16 dead before gated is written

  // 1) fused fp32 -> bf16 conversion (x, W_in, W_dt, W_out): 2M float4
  k_cvt_all<<<dim3(8192), dim3(256), 0, stream>>>(
      x, W_in, W_dt, W_out, xbf, Win_bf, Wdt_bf, Wout_bf);

  // 2) GEMM1: xr = x @ W_in^T; split -> x_proj, silu_res
  //    tile 128x64, grid 32x32 = 1024 blocks = 4/CU
  k_gemm<1, 128, 64, 32><<<dim3(1024), dim3(256), 0, stream>>>(
      xbf, Win_bf, x_proj, silu_res, nullptr, NROW, 2 * DI, DM);

  // 3) causal depthwise conv + silu
  k_conv<<<dim3((unsigned)(MD / 256)), dim3(256), 0, stream>>>(x_proj, conv_w, conv_b, xc_f32, xc_bf);

  // 4) GEMM2: delta = softplus(xc @ W_dt^T + b_dt)
  //    tile 64x64, grid 16x64 = 1024 blocks = 4/CU
  k_gemm<2, 64, 64, 16><<<dim3(1024), dim3(256), 0, stream>>>(
      xc_bf, Wdt_bf, delta, nullptr, b_dt, NROW, DI, DI);

  // 5) chunked selective scan
  k_scanA<<<dim3(BATCH * NCHUNK * (DI / 256)), dim3(256), 0, stream>>>(
      delta, xc_f32, A_log, Bp, hfin, sumdt);
  k_combine<<<dim3(BATCH * NSTATE * DI / 256), dim3(256), 0, stream>>>(
      hfin, sumdt, A_log, hstart);
  k_scanB<<<dim3(BATCH * NCHUNK * (DI / 256)), dim3(256), 0, stream>>>(
      delta, xc_f32, A_log, Bp, Cp, Dp, silu_res, hstart, gated);

  // 6) GEMM3: out = gated @ W_out^T
  //    tile 64x64, grid 16x64 = 1024 blocks = 4/CU
  k_gemm<0, 64, 64, 16><<<dim3(1024), dim3(256), 0, stream>>>(
      gated, Wout_bf, out, nullptr, nullptr, NROW, DM, DI);
}

// Round 6
// 161.894 us; speedup vs baseline: 1.1400x; 1.0392x over previous
//
#include <hip/hip_runtime.h>

typedef unsigned short u16;
typedef __bf16 bf16;
typedef bf16 bf16x8 __attribute__((ext_vector_type(8)));
typedef float f32x4 __attribute__((ext_vector_type(4)));

#define SEQ     2048
#define BATCH   2
#define DM      1024
#define DI      1024
#define NROW    (BATCH*SEQ)      // 4096
#define NSTATE  16
#define NCHUNK  64
#define CLEN    32               // SEQ / NCHUNK
#define BK      64               // K-step (u16 elems); rows are 128B -> swizzled

static_assert(SEQ == NCHUNK * CLEN, "chunking must cover SEQ");

__device__ __forceinline__ u16 f2bf(float f) {
  unsigned u = __builtin_bit_cast(unsigned, f);
  u += 0x7FFFu + ((u >> 16) & 1u);   // round-to-nearest-even
  return (u16)(u >> 16);
}
__device__ __forceinline__ float bf2f(u16 u) {
  return __builtin_bit_cast(float, (unsigned)u << 16);
}
__device__ __forceinline__ float sigm(float x) { return 1.f / (1.f + __expf(-x)); }

// ---------------- fused fp32 -> bf16 convert for all 4 tensors ----------------
// segments (in float4 units): x 1048576 | W_in 524288 | W_dt 262144 | W_out 262144
__global__ __launch_bounds__(256) void k_cvt_all(
    const float* __restrict__ x, const float* __restrict__ Win,
    const float* __restrict__ Wdt, const float* __restrict__ Wout,
    u16* __restrict__ xbf, u16* __restrict__ winbf,
    u16* __restrict__ wdtbf, u16* __restrict__ woutbf)
{
  long i = (long)blockIdx.x * 256 + threadIdx.x;
  const float* src; u16* dst; long off;
  if (i < 1048576)            { src = x;    dst = xbf;    off = i; }
  else if (i < 1572864)       { src = Win;  dst = winbf;  off = i - 1048576; }
  else if (i < 1835008)       { src = Wdt;  dst = wdtbf;  off = i - 1572864; }
  else                        { src = Wout; dst = woutbf; off = i - 1835008; }
  float4 v = reinterpret_cast<const float4*>(src)[off];
  ushort4 o;
  o.x = f2bf(v.x); o.y = f2bf(v.y); o.z = f2bf(v.z); o.w = f2bf(v.w);
  reinterpret_cast<ushort4*>(dst)[off] = o;
}

// ---------------- bf16 MFMA GEMM: C[M][N] = A[M][K] * B[N][K]^T ----------------
// 2-buffer prefetch loop, BK=64, XOR-swizzled LDS (both-sides: pre-swizzled
// global source for global_load_lds + swizzled ds_read) -> conflict-free b128.
// LDS[r][slot] (slot = 16B granule 0..7) holds global slot (slot ^ (r&7)).
// EPI 0: fp32 store  EPI 1: fp32 x_proj / bf16 silu(res)  EPI 2: bf16 softplus

__device__ __forceinline__ void gload16(const u16* g, u16* l) {
  __builtin_amdgcn_global_load_lds((const __attribute__((address_space(1))) void*)g,
                                   (__attribute__((address_space(3))) void*)l,
                                   16, 0, 0);
}

template<int EPI, int BM, int BN, int GX>
__global__ __launch_bounds__(256, 4) void k_gemm(
    const u16* __restrict__ A, const u16* __restrict__ B,
    float* __restrict__ outf, u16* __restrict__ outb,
    const float* __restrict__ bias, int M, int N, int K)
{
  constexpr int MI_ = BM / 32;     // M-frags per wave (2x2 wave grid)
  constexpr int NI_ = BN / 32;     // N-frags per wave
  __shared__ __align__(16) u16 sA[2 * BM * BK];
  __shared__ __align__(16) u16 sB[2 * BN * BK];
  const int t = threadIdx.x;
  const int wave = t >> 6, lane = t & 63;
  const int lr = lane & 15, kb = lane >> 4;
  const int wr = wave >> 1, wc = wave & 1;

  // XCD-aware bijective swizzle (nwg % 8 == 0)
  const int nwg = gridDim.x;
  const int bid = blockIdx.x;
  const int wg  = (bid & 7) * (nwg >> 3) + (bid >> 3);
  const long bm = (long)(wg / GX) * BM;
  const long bn = (long)(wg % GX) * BN;

  f32x4 acc[MI_][NI_] = {};

  // Staging: each call covers 32 rows x 64 cols (u16) = 4096B = 256 thr x 16B.
  // thread t -> row (t>>3), LDS slot (t&7); global slot = (t&7) ^ (row&7).
  const int srow = t >> 3;                               // 0..31
  const int gslot8 = (((t & 7) ^ (srow & 7)) * 8);       // pre-swizzled source
  const u16* gA0 = A + (bm + srow) * (long)K + gslot8;
  const u16* gB0 = B + (bn + srow) * (long)K + gslot8;

  auto STAGE = [&](int buf, int k0) {
    #pragma unroll
    for (int i = 0; i < BM / 32; ++i)
      gload16(gA0 + (long)i * 32 * K + k0,
              &sA[buf * (BM * BK) + i * 2048 + wave * 512]);
    #pragma unroll
    for (int i = 0; i < BN / 32; ++i)
      gload16(gB0 + (long)i * 32 * K + k0,
              &sB[buf * (BN * BK) + i * 2048 + wave * 512]);
  };

  const int xr8 = (lr & 7) * 8;     // read-side XOR (u16 units)
  STAGE(0, 0);
  __syncthreads();
  int cur = 0;
  for (int k0 = 0; k0 < K; k0 += BK) {
    if (k0 + BK < K) STAGE(cur ^ 1, k0 + BK);   // prefetch next tile
    const u16* pa = &sA[cur * (BM * BK)];
    const u16* pb = &sB[cur * (BN * BK)];
    bf16x8 af[2][MI_], bfr[2][NI_];
    #pragma unroll
    for (int kk = 0; kk < 2; ++kk) {
      const int co = ((kb * 8 + kk * 32) ^ xr8);
      #pragma unroll
      for (int mi = 0; mi < MI_; ++mi)
        af[kk][mi] = *reinterpret_cast<const bf16x8*>(
            pa + (wr * (BM / 2) + mi * 16 + lr) * BK + co);
      #pragma unroll
      for (int ni = 0; ni < NI_; ++ni)
        bfr[kk][ni] = *reinterpret_cast<const bf16x8*>(
            pb + (wc * (BN / 2) + ni * 16 + lr) * BK + co);
    }
    #pragma unroll
    for (int kk = 0; kk < 2; ++kk)
      #pragma unroll
      for (int mi = 0; mi < MI_; ++mi)
        #pragma unroll
        for (int ni = 0; ni < NI_; ++ni)
          acc[mi][ni] = __builtin_amdgcn_mfma_f32_16x16x32_bf16(
              af[kk][mi], bfr[kk][ni], acc[mi][ni], 0, 0, 0);
    __syncthreads();   // drains vmcnt(0): next buf staged; cur reads complete
    cur ^= 1;
  }

  #pragma unroll
  for (int mi = 0; mi < MI_; ++mi) {
    const long row0 = bm + wr * (BM / 2) + mi * 16 + kb * 4;  // C/D row=(lane>>4)*4+j
    #pragma unroll
    for (int ni = 0; ni < NI_; ++ni) {
      const long col = bn + wc * (BN / 2) + ni * 16 + lr;     // C/D col=lane&15
      #pragma unroll
      for (int j = 0; j < 4; ++j) {
        const float v = acc[mi][ni][j];
        const long r = row0 + j;
        if (EPI == 0) {
          outf[r * N + col] = v;
        } else if (EPI == 1) {
          if (col < DI) outf[r * DI + col] = v;               // x_proj fp32
          else          outb[r * DI + (col - DI)] = f2bf(v * sigm(v)); // silu bf16
        } else {
          float z = v + bias[col];
          outb[r * N + col] = f2bf(fmaxf(z, 0.f) + log1pf(__expf(-fabsf(z))));
        }
      }
    }
  }
}

// ---------------- causal depthwise conv (K=4) + silu -> bf16 ----------------
__global__ void k_conv(const float* __restrict__ xproj, const float* __restrict__ convw,
                       const float* __restrict__ convb, u16* __restrict__ xcbf)
{
  const int idx = blockIdx.x * 256 + threadIdx.x;   // (m,d), m = b*SEQ+l
  const int d = idx & (DI - 1);
  const int m = idx >> 10;
  const int l = m & (SEQ - 1);
  float acc = convb[d];
  #pragma unroll
  for (int k = 0; k < 4; ++k) {
    int ls = l + k - 3;
    if (ls >= 0)
      acc = fmaf(convw[d * 4 + k], xproj[(long)(m + k - 3) * DI + d], acc);
  }
  float s = acc * sigm(acc);
  xcbf[idx] = f2bf(s);
}

// ---------------- selective scan, chunked (bf16 inputs) ----------------
__global__ __launch_bounds__(256) void k_scanA(
    const u16* __restrict__ delta, const u16* __restrict__ xc,
    const float* __restrict__ A_log, const float* __restrict__ Bp,
    float* __restrict__ hfin, float* __restrict__ sumdt_buf)
{
  const int tid = threadIdx.x, blk = blockIdx.x;    // 512 blocks
  const int d = (blk & 3) * 256 + tid;
  const int c = (blk >> 2) & (NCHUNK - 1);
  const int b = blk >> 8;
  float Aa[NSTATE], Bb[NSTATE], h[NSTATE];
  #pragma unroll
  for (int n = 0; n < NSTATE; ++n) {
    Aa[n] = -__expf(A_log[d * NSTATE + n]);
    Bb[n] = Bp[d * NSTATE + n];
    h[n] = 0.f;
  }
  const long base = ((long)(b * SEQ + c * CLEN)) * DI + d;
  float sdt = 0.f;
  for (int i = 0; i < CLEN; ++i) {
    float dt = bf2f(delta[base + (long)i * DI]);
    float x  = bf2f(xc[base + (long)i * DI]);
    sdt += dt;
    float dx = dt * x;
    #pragma unroll
    for (int n = 0; n < NSTATE; ++n) {
      float da = __expf(dt * Aa[n]);
      h[n] = fmaf(da, h[n], dx * Bb[n]);
    }
  }
  const long sb = ((long)(b * NCHUNK + c) * NSTATE) * DI + d;
  #pragma unroll
  for (int n = 0; n < NSTATE; ++n) hfin[sb + (long)n * DI] = h[n];
  sumdt_buf[(long)(b * NCHUNK + c) * DI + d] = sdt;
}

__global__ __launch_bounds__(256) void k_combine(
    const float* __restrict__ hfin, const float* __restrict__ sumdt_buf,
    const float* __restrict__ A_log, float* __restrict__ hstart)
{
  const int idx = blockIdx.x * 256 + threadIdx.x;   // 32768 threads
  const int d = idx & (DI - 1);
  const int n = (idx >> 10) & (NSTATE - 1);
  const int b = idx >> 14;
  const float Aa = -__expf(A_log[d * NSTATE + n]);
  float h = 0.f;
  for (int c = 0; c < NCHUNK; ++c) {
    const long sb = ((long)(b * NCHUNK + c) * NSTATE + n) * DI + d;
    hstart[sb] = h;
    float sdt = sumdt_buf[(long)(b * NCHUNK + c) * DI + d];
    h = fmaf(__expf(Aa * sdt), h, hfin[sb]);
  }
}

__global__ __launch_bounds__(256) void k_scanB(
    const u16* __restrict__ delta, const u16* __restrict__ xc,
    const float* __restrict__ A_log, const float* __restrict__ Bp,
    const float* __restrict__ Cp, const float* __restrict__ Dp,
    const u16* __restrict__ sres, const float* __restrict__ hstart,
    u16* __restrict__ gated)
{
  const int tid = threadIdx.x, blk = blockIdx.x;    // 512 blocks
  const int d = (blk & 3) * 256 + tid;
  const int c = (blk >> 2) & (NCHUNK - 1);
  const int b = blk >> 8;
  float Aa[NSTATE], Bb[NSTATE], Cc[NSTATE], h[NSTATE];
  #pragma unroll
  for (int n = 0; n < NSTATE; ++n) {
    Aa[n] = -__expf(A_log[d * NSTATE + n]);
    Bb[n] = Bp[d * NSTATE + n];
    Cc[n] = Cp[d * NSTATE + n];
  }
  const float Dd = Dp[d];
  const long sb = ((long)(b * NCHUNK + c) * NSTATE) * DI + d;
  #pragma unroll
  for (int n = 0; n < NSTATE; ++n) h[n] = hstart[sb + (long)n * DI];
  const long base = ((long)(b * SEQ + c * CLEN)) * DI + d;
  for (int i = 0; i < CLEN; ++i) {
    float dt = bf2f(delta[base + (long)i * DI]);
    float x  = bf2f(xc[base + (long)i * DI]);
    float dx = dt * x;
    float y = 0.f;
    #pragma unroll
    for (int n = 0; n < NSTATE; ++n) {
      float da = __expf(dt * Aa[n]);
      h[n] = fmaf(da, h[n], dx * Bb[n]);
      y = fmaf(h[n], Cc[n], y);
    }
    float xs = fmaf(x, Dd, y);
    float g = xs * bf2f(sres[base + (long)i * DI]);
    gated[base + (long)i * DI] = f2bf(g);
  }
}

// ---------------- host launch ----------------
extern "C" void kernel_launch(void* const* d_in, const int* in_sizes, int n_in,
                              void* d_out, int out_size, void* d_ws, size_t ws_size,
                              hipStream_t stream)
{
  const float* x      = (const float*)d_in[0];
  const float* W_in   = (const float*)d_in[1];
  const float* conv_w = (const float*)d_in[2];
  const float* conv_b = (const float*)d_in[3];
  const float* W_dt   = (const float*)d_in[4];
  const float* b_dt   = (const float*)d_in[5];
  const float* A_log  = (const float*)d_in[6];
  const float* Bp     = (const float*)d_in[7];
  const float* Cp     = (const float*)d_in[8];
  const float* Dp     = (const float*)d_in[9];
  const float* W_out  = (const float*)d_in[10];
  float* out = (float*)d_out;

  const long MD = (long)NROW * DI;          // 4194304

  char* ws = (char*)d_ws;
  float* x_proj   = (float*)ws;             ws += MD * 4;   // fp32 (pre-conv)
  u16*   silu_bf  = (u16*)ws;               ws += MD * 2;   // silu(res) bf16
  u16*   delta_bf = (u16*)ws;               ws += MD * 2;   // softplus out bf16
  u16*   xc_bf    = (u16*)ws;               ws += MD * 2;   // conv+silu bf16
  u16*   xbf      = (u16*)ws;               ws += MD * 2;   // x bf16; later gated
  u16*   Win_bf   = (u16*)ws;               ws += (long)2 * DI * DM * 2;
  u16*   Wdt_bf   = (u16*)ws;               ws += (long)DI * DI * 2;
  u16*   Wout_bf  = (u16*)ws;               ws += (long)DM * DI * 2;
  float* hfin     = (float*)ws;             ws += (long)BATCH * NCHUNK * NSTATE * DI * 4;
  float* sumdt    = (float*)ws;             ws += (long)BATCH * NCHUNK * DI * 4;
  float* hstart   = (float*)ws;             ws += (long)BATCH * NCHUNK * NSTATE * DI * 4;

  u16* gated = xbf;      // alias: x_bf16 dead before gated is written

  // 1) fused fp32 -> bf16 conversion (x, W_in, W_dt, W_out): 2M float4
  k_cvt_all<<<dim3(8192), dim3(256), 0, stream>>>(
      x, W_in, W_dt, W_out, xbf, Win_bf, Wdt_bf, Wout_bf);

  // 2) GEMM1: xr = x @ W_in^T -> x_proj (fp32), silu_res (bf16)
  //    tile 128x64, grid 32x32 = 1024 blocks
  k_gemm<1, 128, 64, 32><<<dim3(1024), dim3(256), 0, stream>>>(
      xbf, Win_bf, x_proj, silu_bf, nullptr, NROW, 2 * DI, DM);

  // 3) causal depthwise conv + silu -> bf16
  k_conv<<<dim3((unsigned)(MD / 256)), dim3(256), 0, stream>>>(
      x_proj, conv_w, conv_b, xc_bf);

  // 4) GEMM2: delta = softplus(xc @ W_dt^T + b_dt) -> bf16
  //    tile 64x64, grid 64x16 = 1024 blocks
  k_gemm<2, 64, 64, 16><<<dim3(1024), dim3(256), 0, stream>>>(
      xc_bf, Wdt_bf, nullptr, delta_bf, b_dt, NROW, DI, DI);

  // 5) chunked selective scan (bf16 in, fp32 state)
  k_scanA<<<dim3(BATCH * NCHUNK * (DI / 256)), dim3(256), 0, stream>>>(
      delta_bf, xc_bf, A_log, Bp, hfin, sumdt);
  k_combine<<<dim3(BATCH * NSTATE * DI / 256), dim3(256), 0, stream>>>(
      hfin, sumdt, A_log, hstart);
  k_scanB<<<dim3(BATCH * NCHUNK * (DI / 256)), dim3(256), 0, stream>>>(
      delta_bf, xc_bf, A_log, Bp, Cp, Dp, silu_bf, hstart, gated);

  // 6) GEMM3: out = gated @ W_out^T (fp32 out)
  //    tile 64x64, grid 64x16 = 1024 blocks
  k_gemm<0, 64, 64, 16><<<dim3(1024), dim3(256), 0, stream>>>(
      gated, Wout_bf, out, nullptr, nullptr, NROW, DM, DI);
}

// Round 7
// 157.211 us; speedup vs baseline: 1.1740x; 1.0298x over previous
//
#include <hip/hip_runtime.h>

typedef unsigned short u16;
typedef __bf16 bf16;
typedef bf16 bf16x8 __attribute__((ext_vector_type(8)));
typedef float f32x16 __attribute__((ext_vector_type(16)));

#define SEQ     2048
#define BATCH   2
#define DM      1024
#define DI      1024
#define NROW    (BATCH*SEQ)      // 4096
#define NSTATE  16
#define NCHUNK  64
#define CLEN    32               // SEQ / NCHUNK
#define BK      64               // K-step (u16 elems); rows are 128B, granule-swizzled

static_assert(SEQ == NCHUNK * CLEN, "chunking must cover SEQ");

__device__ __forceinline__ u16 f2bf(float f) {
  unsigned u = __builtin_bit_cast(unsigned, f);
  u += 0x7FFFu + ((u >> 16) & 1u);   // round-to-nearest-even
  return (u16)(u >> 16);
}
__device__ __forceinline__ float bf2f(u16 u) {
  return __builtin_bit_cast(float, (unsigned)u << 16);
}
__device__ __forceinline__ float sigm(float x) { return 1.f / (1.f + __expf(-x)); }

// ---------------- fused fp32 -> bf16 convert for all 4 tensors ----------------
// segments (in float4 units): x 1048576 | W_in 524288 | W_dt 262144 | W_out 262144
__global__ __launch_bounds__(256) void k_cvt_all(
    const float* __restrict__ x, const float* __restrict__ Win,
    const float* __restrict__ Wdt, const float* __restrict__ Wout,
    u16* __restrict__ xbf, u16* __restrict__ winbf,
    u16* __restrict__ wdtbf, u16* __restrict__ woutbf)
{
  long i = (long)blockIdx.x * 256 + threadIdx.x;
  const float* src; u16* dst; long off;
  if (i < 1048576)            { src = x;    dst = xbf;    off = i; }
  else if (i < 1572864)       { src = Win;  dst = winbf;  off = i - 1048576; }
  else if (i < 1835008)       { src = Wdt;  dst = wdtbf;  off = i - 1572864; }
  else                        { src = Wout; dst = woutbf; off = i - 1835008; }
  float4 v = reinterpret_cast<const float4*>(src)[off];
  ushort4 o;
  o.x = f2bf(v.x); o.y = f2bf(v.y); o.z = f2bf(v.z); o.w = f2bf(v.w);
  reinterpret_cast<ushort4*>(dst)[off] = o;
}

// ---------------- bf16 MFMA GEMM: C[M][N] = A[M][K] * B[N][K]^T ----------------
// 32x32x16 fragments (2x LDS efficiency vs 16x16x32), 2-buffer prefetch loop,
// BK=64, both-sides granule swizzle: LDS[r][slot] holds global granule
// slot ^ (r&7); reads use slot = g ^ (r&7)  (one 16B granule per lane).
// A/B frag: lane l -> row/col (l&31), k = (l>>5)*8 .. +7 (contiguous 8 bf16).
// C/D frag: col = l&31, row = (reg&3) + 8*(reg>>2) + 4*(l>>5).
// EPI 0: fp32 store   EPI 1: bf16 x_proj / bf16 silu(res)   EPI 2: bf16 softplus

__device__ __forceinline__ void gload16(const u16* g, u16* l) {
  __builtin_amdgcn_global_load_lds((const __attribute__((address_space(1))) void*)g,
                                   (__attribute__((address_space(3))) void*)l,
                                   16, 0, 0);
}

template<int EPI, int BM, int BN, int GX>
__global__ __launch_bounds__(256, 2) void k_gemm(
    const u16* __restrict__ A, const u16* __restrict__ B,
    float* __restrict__ outf, u16* __restrict__ outb, u16* __restrict__ outb2,
    const float* __restrict__ bias, int M, int N, int K)
{
  constexpr int MI_ = BM / 64;     // 32x32 frags per wave in M (2x2 wave grid)
  constexpr int NI_ = BN / 64;     // 32x32 frags per wave in N
  __shared__ __align__(16) u16 sA[2 * BM * BK];
  __shared__ __align__(16) u16 sB[2 * BN * BK];
  const int t = threadIdx.x;
  const int wave = t >> 6, lane = t & 63;
  const int la = lane & 31, hi = lane >> 5;
  const int wr = wave >> 1, wc = wave & 1;

  // XCD-aware bijective swizzle (nwg % 8 == 0)
  const int nwg = gridDim.x;
  const int bid = blockIdx.x;
  const int wg  = (bid & 7) * (nwg >> 3) + (bid >> 3);
  const long bm = (long)(wg / GX) * BM;
  const long bn = (long)(wg % GX) * BN;

  f32x16 acc[MI_][NI_] = {};

  // Staging: each call covers 32 rows x 64 cols (u16) = 4096B = 256 thr x 16B.
  // thread t -> row (t>>3), LDS slot (t&7); global granule = (t&7) ^ (row&7).
  const int srow = t >> 3;                               // 0..31
  const int gslot8 = (((t & 7) ^ (srow & 7)) * 8);       // pre-swizzled source
  const u16* gA0 = A + (bm + srow) * (long)K + gslot8;
  const u16* gB0 = B + (bn + srow) * (long)K + gslot8;

  auto STAGE = [&](int buf, int k0) {
    #pragma unroll
    for (int i = 0; i < BM / 32; ++i)
      gload16(gA0 + (long)i * 32 * K + k0,
              &sA[buf * (BM * BK) + i * 2048 + wave * 512]);
    #pragma unroll
    for (int i = 0; i < BN / 32; ++i)
      gload16(gB0 + (long)i * 32 * K + k0,
              &sB[buf * (BN * BK) + i * 2048 + wave * 512]);
  };

  const int xr = la & 7;            // read-side XOR (granule units)
  STAGE(0, 0);
  __syncthreads();
  int cur = 0;
  for (int k0 = 0; k0 < K; k0 += BK) {
    if (k0 + BK < K) STAGE(cur ^ 1, k0 + BK);   // prefetch next tile
    const u16* pa = &sA[cur * (BM * BK)];
    const u16* pb = &sB[cur * (BN * BK)];
    bf16x8 af[4][MI_], bfr[4][NI_];
    #pragma unroll
    for (int ks = 0; ks < 4; ++ks) {
      const int co = ((ks * 2 + hi) ^ xr) * 8;  // granule slot -> u16 offset
      #pragma unroll
      for (int mi = 0; mi < MI_; ++mi)
        af[ks][mi] = *reinterpret_cast<const bf16x8*>(
            pa + (wr * (BM / 2) + mi * 32 + la) * BK + co);
      #pragma unroll
      for (int ni = 0; ni < NI_; ++ni)
        bfr[ks][ni] = *reinterpret_cast<const bf16x8*>(
            pb + (wc * (BN / 2) + ni * 32 + la) * BK + co);
    }
    #pragma unroll
    for (int ks = 0; ks < 4; ++ks)
      #pragma unroll
      for (int mi = 0; mi < MI_; ++mi)
        #pragma unroll
        for (int ni = 0; ni < NI_; ++ni)
          acc[mi][ni] = __builtin_amdgcn_mfma_f32_32x32x16_bf16(
              af[ks][mi], bfr[ks][ni], acc[mi][ni], 0, 0, 0);
    __syncthreads();   // drains vmcnt(0): next buf staged; cur reads complete
    cur ^= 1;
  }

  #pragma unroll
  for (int mi = 0; mi < MI_; ++mi) {
    const long rowb = bm + wr * (BM / 2) + mi * 32 + 4 * hi;
    #pragma unroll
    for (int ni = 0; ni < NI_; ++ni) {
      const long col = bn + wc * (BN / 2) + ni * 32 + la;
      #pragma unroll
      for (int q = 0; q < 4; ++q)
        #pragma unroll
        for (int j = 0; j < 4; ++j) {
          const float v = acc[mi][ni][q * 4 + j];
          const long r = rowb + q * 8 + j;
          if (EPI == 0) {
            outf[r * N + col] = v;
          } else if (EPI == 1) {
            if (bn < DI) outb[r * DI + col] = f2bf(v);                    // x_proj
            else         outb2[r * DI + (col - DI)] = f2bf(v * sigm(v));  // silu(res)
          } else {
            float z = v + bias[col];
            outb[r * N + col] = f2bf(fmaxf(z, 0.f) + log1pf(__expf(-fabsf(z))));
          }
        }
    }
  }
}

// ---------------- causal depthwise conv (K=4) + silu -> bf16 ----------------
__global__ void k_conv(const u16* __restrict__ xproj, const float* __restrict__ convw,
                       const float* __restrict__ convb, u16* __restrict__ xcbf)
{
  const int idx = blockIdx.x * 256 + threadIdx.x;   // (m,d), m = b*SEQ+l
  const int d = idx & (DI - 1);
  const int m = idx >> 10;
  const int l = m & (SEQ - 1);
  float acc = convb[d];
  #pragma unroll
  for (int k = 0; k < 4; ++k) {
    int ls = l + k - 3;
    if (ls >= 0)
      acc = fmaf(convw[d * 4 + k], bf2f(xproj[(long)(m + k - 3) * DI + d]), acc);
  }
  float s = acc * sigm(acc);
  xcbf[idx] = f2bf(s);
}

// ---------------- selective scan, chunked (bf16 inputs) ----------------
__global__ __launch_bounds__(256) void k_scanA(
    const u16* __restrict__ delta, const u16* __restrict__ xc,
    const float* __restrict__ A_log, const float* __restrict__ Bp,
    float* __restrict__ hfin, float* __restrict__ sumdt_buf)
{
  const int tid = threadIdx.x, blk = blockIdx.x;    // 512 blocks
  const int d = (blk & 3) * 256 + tid;
  const int c = (blk >> 2) & (NCHUNK - 1);
  const int b = blk >> 8;
  float Aa[NSTATE], Bb[NSTATE], h[NSTATE];
  #pragma unroll
  for (int n = 0; n < NSTATE; ++n) {
    Aa[n] = -__expf(A_log[d * NSTATE + n]);
    Bb[n] = Bp[d * NSTATE + n];
    h[n] = 0.f;
  }
  const long base = ((long)(b * SEQ + c * CLEN)) * DI + d;
  float sdt = 0.f;
  for (int i = 0; i < CLEN; ++i) {
    float dt = bf2f(delta[base + (long)i * DI]);
    float x  = bf2f(xc[base + (long)i * DI]);
    sdt += dt;
    float dx = dt * x;
    #pragma unroll
    for (int n = 0; n < NSTATE; ++n) {
      float da = __expf(dt * Aa[n]);
      h[n] = fmaf(da, h[n], dx * Bb[n]);
    }
  }
  const long sb = ((long)(b * NCHUNK + c) * NSTATE) * DI + d;
  #pragma unroll
  for (int n = 0; n < NSTATE; ++n) hfin[sb + (long)n * DI] = h[n];
  sumdt_buf[(long)(b * NCHUNK + c) * DI + d] = sdt;
}

__global__ __launch_bounds__(256) void k_combine(
    const float* __restrict__ hfin, const float* __restrict__ sumdt_buf,
    const float* __restrict__ A_log, float* __restrict__ hstart)
{
  const int idx = blockIdx.x * 256 + threadIdx.x;   // 32768 threads
  const int d = idx & (DI - 1);
  const int n = (idx >> 10) & (NSTATE - 1);
  const int b = idx >> 14;
  const float Aa = -__expf(A_log[d * NSTATE + n]);
  float h = 0.f;
  for (int c = 0; c < NCHUNK; ++c) {
    const long sb = ((long)(b * NCHUNK + c) * NSTATE + n) * DI + d;
    hstart[sb] = h;
    float sdt = sumdt_buf[(long)(b * NCHUNK + c) * DI + d];
    h = fmaf(__expf(Aa * sdt), h, hfin[sb]);
  }
}

__global__ __launch_bounds__(256) void k_scanB(
    const u16* __restrict__ delta, const u16* __restrict__ xc,
    const float* __restrict__ A_log, const float* __restrict__ Bp,
    const float* __restrict__ Cp, const float* __restrict__ Dp,
    const u16* __restrict__ sres, const float* __restrict__ hstart,
    u16* __restrict__ gated)
{
  const int tid = threadIdx.x, blk = blockIdx.x;    // 512 blocks
  const int d = (blk & 3) * 256 + tid;
  const int c = (blk >> 2) & (NCHUNK - 1);
  const int b = blk >> 8;
  float Aa[NSTATE], Bb[NSTATE], Cc[NSTATE], h[NSTATE];
  #pragma unroll
  for (int n = 0; n < NSTATE; ++n) {
    Aa[n] = -__expf(A_log[d * NSTATE + n]);
    Bb[n] = Bp[d * NSTATE + n];
    Cc[n] = Cp[d * NSTATE + n];
  }
  const float Dd = Dp[d];
  const long sb = ((long)(b * NCHUNK + c) * NSTATE) * DI + d;
  #pragma unroll
  for (int n = 0; n < NSTATE; ++n) h[n] = hstart[sb + (long)n * DI];
  const long base = ((long)(b * SEQ + c * CLEN)) * DI + d;
  for (int i = 0; i < CLEN; ++i) {
    float dt = bf2f(delta[base + (long)i * DI]);
    float x  = bf2f(xc[base + (long)i * DI]);
    float dx = dt * x;
    float y = 0.f;
    #pragma unroll
    for (int n = 0; n < NSTATE; ++n) {
      float da = __expf(dt * Aa[n]);
      h[n] = fmaf(da, h[n], dx * Bb[n]);
      y = fmaf(h[n], Cc[n], y);
    }
    float xs = fmaf(x, Dd, y);
    float g = xs * bf2f(sres[base + (long)i * DI]);
    gated[base + (long)i * DI] = f2bf(g);
  }
}

// ---------------- host launch ----------------
extern "C" void kernel_launch(void* const* d_in, const int* in_sizes, int n_in,
                              void* d_out, int out_size, void* d_ws, size_t ws_size,
                              hipStream_t stream)
{
  const float* x      = (const float*)d_in[0];
  const float* W_in   = (const float*)d_in[1];
  const float* conv_w = (const float*)d_in[2];
  const float* conv_b = (const float*)d_in[3];
  const float* W_dt   = (const float*)d_in[4];
  const float* b_dt   = (const float*)d_in[5];
  const float* A_log  = (const float*)d_in[6];
  const float* Bp     = (const float*)d_in[7];
  const float* Cp     = (const float*)d_in[8];
  const float* Dp     = (const float*)d_in[9];
  const float* W_out  = (const float*)d_in[10];
  float* out = (float*)d_out;

  const long MD = (long)NROW * DI;          // 4194304

  char* ws = (char*)d_ws;
  u16*   xproj_bf = (u16*)ws;               ws += MD * 2;   // x_proj bf16
  u16*   silu_bf  = (u16*)ws;               ws += MD * 2;   // silu(res) bf16
  u16*   delta_bf = (u16*)ws;               ws += MD * 2;   // softplus out bf16
  u16*   xc_bf    = (u16*)ws;               ws += MD * 2;   // conv+silu bf16
  u16*   xbf      = (u16*)ws;               ws += MD * 2;   // x bf16; later gated
  u16*   Win_bf   = (u16*)ws;               ws += (long)2 * DI * DM * 2;
  u16*   Wdt_bf   = (u16*)ws;               ws += (long)DI * DI * 2;
  u16*   Wout_bf  = (u16*)ws;               ws += (long)DM * DI * 2;
  float* hfin     = (float*)ws;             ws += (long)BATCH * NCHUNK * NSTATE * DI * 4;
  float* sumdt    = (float*)ws;             ws += (long)BATCH * NCHUNK * DI * 4;
  float* hstart   = (float*)ws;             ws += (long)BATCH * NCHUNK * NSTATE * DI * 4;

  u16* gated = xbf;      // alias: x_bf16 dead before gated is written

  // 1) fused fp32 -> bf16 conversion (x, W_in, W_dt, W_out): 2M float4
  k_cvt_all<<<dim3(8192), dim3(256), 0, stream>>>(
      x, W_in, W_dt, W_out, xbf, Win_bf, Wdt_bf, Wout_bf);

  // 2) GEMM1: xr = x @ W_in^T -> x_proj (bf16), silu_res (bf16)
  //    tile 128x128, grid 32x16 = 512 blocks (2/CU), 64KB LDS
  k_gemm<1, 128, 128, 16><<<dim3(512), dim3(256), 0, stream>>>(
      xbf, Win_bf, nullptr, xproj_bf, silu_bf, nullptr, NROW, 2 * DI, DM);

  // 3) causal depthwise conv + silu -> bf16
  k_conv<<<dim3((unsigned)(MD / 256)), dim3(256), 0, stream>>>(
      xproj_bf, conv_w, conv_b, xc_bf);

  // 4) GEMM2: delta = softplus(xc @ W_dt^T + b_dt) -> bf16
  //    tile 64x64, grid 64x16 = 1024 blocks (4/CU), 32KB LDS
  k_gemm<2, 64, 64, 16><<<dim3(1024), dim3(256), 0, stream>>>(
      xc_bf, Wdt_bf, nullptr, delta_bf, nullptr, b_dt, NROW, DI, DI);

  // 5) chunked selective scan (bf16 in, fp32 state)
  k_scanA<<<dim3(BATCH * NCHUNK * (DI / 256)), dim3(256), 0, stream>>>(
      delta_bf, xc_bf, A_log, Bp, hfin, sumdt);
  k_combine<<<dim3(BATCH * NSTATE * DI / 256), dim3(256), 0, stream>>>(
      hfin, sumdt, A_log, hstart);
  k_scanB<<<dim3(BATCH * NCHUNK * (DI / 256)), dim3(256), 0, stream>>>(
      delta_bf, xc_bf, A_log, Bp, Cp, Dp, silu_bf, hstart, gated);

  // 6) GEMM3: out = gated @ W_out^T (fp32 out)
  //    tile 64x64, grid 64x16 = 1024 blocks (4/CU), 32KB LDS
  k_gemm<0, 64, 64, 16><<<dim3(1024), dim3(256), 0, stream>>>(
      gated, Wout_bf, out, nullptr, nullptr, nullptr, NROW, DM, DI);
}